// Round 8
// baseline (343.540 us; speedup 1.0000x reference)
//
#include <hip/hip_runtime.h>
#include <math.h>

#define BB 32
#define LL 2048
#define EE 512
#define HH 512

typedef __bf16 bf16_t;
typedef bf16_t bf16x8 __attribute__((ext_vector_type(8)));
typedef float f32x4 __attribute__((ext_vector_type(4)));
typedef unsigned short u16x8 __attribute__((ext_vector_type(8)));

__device__ __forceinline__ unsigned short f2bf(float f) {
  unsigned int u = __builtin_bit_cast(unsigned int, f);
  unsigned int r = (u + 0x7FFFu + ((u >> 16) & 1u)) >> 16;  // RNE
  return (unsigned short)r;
}
__device__ __forceinline__ float bf2f(unsigned short s) {
  unsigned int u = ((unsigned int)s) << 16;
  return __builtin_bit_cast(float, u);
}
__device__ __forceinline__ bf16x8 ld_frag(const unsigned short* p) {
  u16x8 raw = *(const u16x8*)p;
  return __builtin_bit_cast(bf16x8, raw);
}
__device__ __forceinline__ float tanh_fast(float x) {
  x = fminf(fmaxf(x, -15.f), 15.f);
  float e2 = __expf(2.f * x);
  return (e2 - 1.f) / (e2 + 1.f);
}

// load the 4 A-frags of one 64-row x 32-k weight window DIRECTLY global->reg in MFMA
// layout (row wbase+t*16+l15, 16B at k0+quad*8 -- contiguous per lane). The R0/R7
// LDS slab was only a latency buffer, and it cost 3/4 of the k-loop's LDS ops plus
// 64 KB of LDS (the occupancy cap). Latency is covered by the distance-2 register
// double-buffer x 4 waves/SIMD TLP (2 blocks/CU now that LDS fits).
__device__ __forceinline__ void frag_issue(const unsigned short* __restrict__ g,
                                           int k0, bf16x8 f[4]) {
#pragma unroll
  for (int i = 0; i < 4; i++) f[i] = ld_frag(g + (size_t)i * 16 * 512 + k0);
}

// ---------------- prep: transpose + fp32->bf16 convert of Wh, Wc; init work queue ----------------
__global__ __launch_bounds__(256) void prep_w(
    const float* __restrict__ Wh, const float* __restrict__ Wc,
    unsigned short* __restrict__ WhT, unsigned short* __restrict__ WcT,
    int* __restrict__ q)
{
  if (blockIdx.x == 0 && blockIdx.y == 0 && threadIdx.x == 0) *q = 0;
  const float* src = blockIdx.y ? Wc : Wh;
  unsigned short* dst = blockIdx.y ? WcT : WhT;
  const int tr = (blockIdx.x >> 3) * 64;
  const int tc = (blockIdx.x & 7) * 64;
  const int tid = threadIdx.x;
  __shared__ float tile[64][65];
  for (int i = tid; i < 64 * 16; i += 256) {
    const int r = i >> 4, c4 = (i & 15) << 2;
    const float4 v = *(const float4*)(src + (size_t)(tr + r) * 512 + tc + c4);
    tile[r][c4 + 0] = v.x; tile[r][c4 + 1] = v.y;
    tile[r][c4 + 2] = v.z; tile[r][c4 + 3] = v.w;
  }
  __syncthreads();
  for (int i = tid; i < 64 * 16; i += 256) {
    const int r = i >> 4, c4 = (i & 15) << 2;
    ushort4 pk;
    pk.x = f2bf(tile[c4 + 0][r]); pk.y = f2bf(tile[c4 + 1][r]);
    pk.z = f2bf(tile[c4 + 2][r]); pk.w = f2bf(tile[c4 + 3][r]);
    *(ushort4*)(dst + (size_t)(tc + r) * 512 + tr + c4) = pk;
  }
}

// ---------------- main: R7 structure (cross-item enc prefetch) + direct-global weight frags ----------------
// LDS = ebuf(66.6) + bh(2) ~= 68.6 KB -> 2 blocks/CU when VGPR <= 128 (compiler
// already lands exactly on 128 for this shape under (512,2)). Two barrier domains
// overlap phase stalls; 4 waves/SIMD cover the frag loads' L2 latency.
__global__ __launch_bounds__(512, 2) void attn_main(
    const float* __restrict__ enc, const int* __restrict__ lens,
    const unsigned short* __restrict__ WhT, const float* __restrict__ bh,
    const unsigned short* __restrict__ WcT,
    float* __restrict__ pm, float* __restrict__ ps, float* __restrict__ po,
    int* __restrict__ q, int C, int Lc)
{
  const int tid  = threadIdx.x;
  const int wave = tid >> 6;       // 0..7
  const int lane = tid & 63;
  const int quad = lane >> 4;
  const int l15  = lane & 15;
  const int wbase = wave * 64;     // wave's 64-wide h-slab (GEMM1) / e-slab (GEMM2)

  __shared__ __align__(16) unsigned short ebuf[2][32 * 520];  // 66.6 KB (enc/h ping-pong)
  __shared__ __align__(16) float bhS[512];
  __shared__ int itemS;

  bhS[tid] = bh[tid];
  const int nitems = 32 * C;

  // ---- prologue: pop first VALID item (tid0 skips empty chunks without barriers) ----
  if (tid == 0) {
    int it;
    for (;;) {
      it = atomicAdd(q, 1);
      if (it >= nitems || lens[it & 31] > (it >> 5) * Lc) break;
    }
    itemS = it;
  }
  __syncthreads();
  int item = itemS;
  int p = 0;

  float4 eR[8];  // next enc tile in flight (32 regs; dead during GEMM1/pack)
  if (item < nitems) {
    const float* src = enc + ((size_t)(item & 31) * LL + (size_t)(item >> 5) * Lc) * EE;
#pragma unroll
    for (int k = 0; k < 8; k++) {
      const int i = tid + k * 512;
      eR[k] = *(const float4*)(src + (size_t)(i >> 7) * EE + ((i & 127) << 2));
    }
  }

#pragma unroll 1
  for (;;) {
    if (item >= nitems) break;
    const int b = item & 31;
    const int c = item >> 5;
    const int l0 = c * Lc;
    const int nvalid = min(lens[b] - l0, Lc);   // >= 1 (pop skips invalid)
    const int phase = (item + wave) & 15;       // k-window de-phasing
    unsigned short* encA = ebuf[p];
    unsigned short* hS   = ebuf[p ^ 1];

    float stM[4], stS[4], stO[4];
#pragma unroll
    for (int et = 0; et < 4; et++) { stM[et] = -1e30f; stS[et] = 0.f; stO[et] = 0.f; }

    int nextItem = nitems;

#pragma unroll 1
    for (int r0 = 0; r0 < nvalid; r0 += 32) {
      const bool lastPass = (r0 + 32 >= nvalid);

      // ---- stage: pass 0 writes the PREFETCHED regs; later passes load synchronously ----
      if (r0 == 0) {
#pragma unroll
        for (int k = 0; k < 8; k++) {
          const int i = tid + k * 512;
          const float4 v = eR[k];
          ushort4 pk;
          pk.x = f2bf(v.x); pk.y = f2bf(v.y); pk.z = f2bf(v.z); pk.w = f2bf(v.w);
          *(ushort4*)&encA[(i >> 7) * 520 + ((i & 127) << 2)] = pk;
        }
      } else {
        const float* encRow = enc + ((size_t)b * LL + l0 + r0) * EE;
        for (int i = tid; i < 32 * 128; i += 512) {
          const int m = i >> 7, e4 = (i & 127) << 2;
          const float4 v = *(const float4*)(encRow + (size_t)m * EE + e4);
          ushort4 pk;
          pk.x = f2bf(v.x); pk.y = f2bf(v.y); pk.z = f2bf(v.z); pk.w = f2bf(v.w);
          *(ushort4*)&encA[m * 520 + e4] = pk;
        }
      }
      // pop next valid item while others stage; published by the barrier below
      if (lastPass && tid == 0) {
        int it;
        for (;;) {
          it = atomicAdd(q, 1);
          if (it >= nitems || lens[it & 31] > (it >> 5) * Lc) break;
        }
        itemS = it;
      }
      __syncthreads();

      // ================= GEMM1: hT[64 x 32] per wave = WhT @ encT =================
      f32x4 acc1[4][2];
#pragma unroll
      for (int t = 0; t < 4; t++)
        for (int mt = 0; mt < 2; mt++) acc1[t][mt] = (f32x4){0.f, 0.f, 0.f, 0.f};
      {
        const unsigned short* baseW = WhT + (size_t)(wbase + l15) * 512 + quad * 8;
        bf16x8 fA[4], fB[4];
        frag_issue(baseW, ((0 + phase) & 15) * 32, fA);
        frag_issue(baseW, ((1 + phase) & 15) * 32, fB);
#pragma unroll 1
        for (int kk = 0; kk < 16; kk += 2) {
          {
            const int k0 = ((kk + phase) & 15) * 32;
            const bf16x8 b0 = ld_frag(&encA[l15 * 520 + k0 + quad * 8]);
            const bf16x8 b1 = ld_frag(&encA[(16 + l15) * 520 + k0 + quad * 8]);
#pragma unroll
            for (int t = 0; t < 4; t++) {
              acc1[t][0] = __builtin_amdgcn_mfma_f32_16x16x32_bf16(fA[t], b0, acc1[t][0], 0, 0, 0);
              acc1[t][1] = __builtin_amdgcn_mfma_f32_16x16x32_bf16(fA[t], b1, acc1[t][1], 0, 0, 0);
            }
            if (kk + 2 < 16) frag_issue(baseW, ((kk + 2 + phase) & 15) * 32, fA);
          }
          {
            const int k0 = ((kk + 1 + phase) & 15) * 32;
            const bf16x8 b0 = ld_frag(&encA[l15 * 520 + k0 + quad * 8]);
            const bf16x8 b1 = ld_frag(&encA[(16 + l15) * 520 + k0 + quad * 8]);
#pragma unroll
            for (int t = 0; t < 4; t++) {
              acc1[t][0] = __builtin_amdgcn_mfma_f32_16x16x32_bf16(fB[t], b0, acc1[t][0], 0, 0, 0);
              acc1[t][1] = __builtin_amdgcn_mfma_f32_16x16x32_bf16(fB[t], b1, acc1[t][1], 0, 0, 0);
            }
            if (kk + 3 < 16) frag_issue(baseW, ((kk + 3 + phase) & 15) * 32, fB);
          }
        }
      }

      // ---- bias + tanh, pack 4 consecutive h -> one 8B LDS write of h[m][h] ----
#pragma unroll
      for (int t = 0; t < 4; t++) {
        const f32x4 bv = *(const f32x4*)&bhS[wbase + t * 16 + quad * 4];
#pragma unroll
        for (int mt = 0; mt < 2; mt++) {
          ushort4 pk;
          pk.x = f2bf(tanh_fast(acc1[t][mt][0] + bv[0]));
          pk.y = f2bf(tanh_fast(acc1[t][mt][1] + bv[1]));
          pk.z = f2bf(tanh_fast(acc1[t][mt][2] + bv[2]));
          pk.w = f2bf(tanh_fast(acc1[t][mt][3] + bv[3]));
          *(ushort4*)&hS[(mt * 16 + l15) * 520 + wbase + t * 16 + quad * 4] = pk;
        }
      }
      __syncthreads();

      // ================= GEMM2: logits[32 x 64] per wave = h @ WcT-slab =================
      f32x4 acc2[2][4];
#pragma unroll
      for (int mt = 0; mt < 2; mt++)
        for (int et = 0; et < 4; et++) acc2[mt][et] = (f32x4){0.f, 0.f, 0.f, 0.f};
      {
        const unsigned short* baseW = WcT + (size_t)(wbase + l15) * 512 + quad * 8;
        bf16x8 fA[4], fB[4];
        frag_issue(baseW, ((0 + phase) & 15) * 32, fA);
        frag_issue(baseW, ((1 + phase) & 15) * 32, fB);
#pragma unroll 1
        for (int kk = 0; kk < 16; kk += 2) {
          {
            const int k0 = ((kk + phase) & 15) * 32;
            const bf16x8 a0 = ld_frag(&hS[l15 * 520 + k0 + quad * 8]);
            const bf16x8 a1 = ld_frag(&hS[(16 + l15) * 520 + k0 + quad * 8]);
#pragma unroll
            for (int et = 0; et < 4; et++) {
              acc2[0][et] = __builtin_amdgcn_mfma_f32_16x16x32_bf16(a0, fA[et], acc2[0][et], 0, 0, 0);
              acc2[1][et] = __builtin_amdgcn_mfma_f32_16x16x32_bf16(a1, fA[et], acc2[1][et], 0, 0, 0);
            }
            if (kk + 2 < 16) frag_issue(baseW, ((kk + 2 + phase) & 15) * 32, fA);
          }
          {
            const int k0 = ((kk + 1 + phase) & 15) * 32;
            const bf16x8 a0 = ld_frag(&hS[l15 * 520 + k0 + quad * 8]);
            const bf16x8 a1 = ld_frag(&hS[(16 + l15) * 520 + k0 + quad * 8]);
#pragma unroll
            for (int et = 0; et < 4; et++) {
              acc2[0][et] = __builtin_amdgcn_mfma_f32_16x16x32_bf16(a0, fB[et], acc2[0][et], 0, 0, 0);
              acc2[1][et] = __builtin_amdgcn_mfma_f32_16x16x32_bf16(a1, fB[et], acc2[1][et], 0, 0, 0);
            }
            if (kk + 3 < 16) frag_issue(baseW, ((kk + 3 + phase) & 15) * 32, fB);
          }
        }
      }

      // ---- issue NEXT item's enc loads (newest in vmcnt FIFO; latency hides under softmax) ----
      if (lastPass) {
        nextItem = itemS;
        if (nextItem < nitems) {
          const float* src = enc + ((size_t)(nextItem & 31) * LL + (size_t)(nextItem >> 5) * Lc) * EE;
#pragma unroll
          for (int k = 0; k < 8; k++) {
            const int i = tid + k * 512;
            eR[k] = *(const float4*)(src + (size_t)(i >> 7) * EE + ((i & 127) << 2));
          }
        }
      }

      // ---- masked online softmax over the 32 time rows of this pass ----
      bool ok[2][4];
#pragma unroll
      for (int mt = 0; mt < 2; mt++)
#pragma unroll
        for (int r = 0; r < 4; r++)
          ok[mt][r] = (r0 + mt * 16 + quad * 4 + r) < nvalid;

#pragma unroll
      for (int et = 0; et < 4; et++) {
        const int e = wbase + et * 16 + l15;
        float v[2][4];
        float lm = -1e30f;
#pragma unroll
        for (int mt = 0; mt < 2; mt++)
#pragma unroll
          for (int r = 0; r < 4; r++) {
            v[mt][r] = ok[mt][r] ? acc2[mt][et][r] : -1e30f;
            lm = fmaxf(lm, v[mt][r]);
          }
        lm = fmaxf(lm, __shfl_xor(lm, 16));
        lm = fmaxf(lm, __shfl_xor(lm, 32));
        float ls = 0.f, lo = 0.f;
#pragma unroll
        for (int mt = 0; mt < 2; mt++)
#pragma unroll
          for (int r = 0; r < 4; r++) {
            const float pexp = __expf(v[mt][r] - lm);
            const float ev = bf2f(encA[(mt * 16 + quad * 4 + r) * 520 + e]);
            ls += pexp;
            lo += pexp * ev;
          }
        ls += __shfl_xor(ls, 16); ls += __shfl_xor(ls, 32);
        lo += __shfl_xor(lo, 16); lo += __shfl_xor(lo, 32);
        const float Mn = fmaxf(stM[et], lm);
        const float sc = __expf(stM[et] - Mn);
        const float st = __expf(lm - Mn);
        stS[et] = stS[et] * sc + ls * st;
        stO[et] = stO[et] * sc + lo * st;
        stM[et] = Mn;
      }
      __syncthreads();   // end of pass: all reads of encA/hS complete
    }

    if (quad == 0) {
      const size_t base = ((size_t)b * C + c) * EE;
#pragma unroll
      for (int et = 0; et < 4; et++) {
        const int e = wbase + et * 16 + l15;
        pm[base + e] = stM[et];
        ps[base + e] = stS[et];
        po[base + e] = stO[et];
      }
    }

    item = nextItem;
    p ^= 1;
  }
}

// ---------------- combine over chunks (parallelized: 8 e-slabs x 4 c-groups) ----------------
__global__ __launch_bounds__(256) void attn_combine(
    const float* __restrict__ pm, const float* __restrict__ ps,
    const float* __restrict__ po, const int* __restrict__ lens,
    float* __restrict__ out, int C, int Lc)
{
  const int b  = blockIdx.y;
  const int e  = blockIdx.x * 64 + (threadIdx.x & 63);
  const int g  = threadIdx.x >> 6;  // c-group 0..3
  const int n  = lens[b];
  const int cmax = min(C, (n + Lc - 1) / Lc);

  float M = -1e30f, S = 0.f, O = 0.f;
  for (int c = g; c < cmax; c += 4) {
    const size_t base = ((size_t)b * C + c) * EE;
    const float m = pm[base + e];
    const float s = ps[base + e];
    const float o = po[base + e];
    const float Mn  = fmaxf(M, m);
    const float sc0 = __expf(M - Mn);
    const float sc1 = __expf(m - Mn);
    S = S * sc0 + s * sc1;
    O = O * sc0 + o * sc1;
    M = Mn;
  }

  __shared__ float sM[4][64], sS[4][64], sO[4][64];
  sM[g][threadIdx.x & 63] = M;
  sS[g][threadIdx.x & 63] = S;
  sO[g][threadIdx.x & 63] = O;
  __syncthreads();

  if (g == 0) {
    const int le = threadIdx.x & 63;
    float Mt = sM[0][le], St = sS[0][le], Ot = sO[0][le];
#pragma unroll
    for (int gg = 1; gg < 4; gg++) {
      const float m = sM[gg][le];
      const float Mn  = fmaxf(Mt, m);
      const float sc0 = __expf(Mt - Mn);
      const float sc1 = __expf(m - Mn);
      St = St * sc0 + sS[gg][le] * sc1;
      Ot = Ot * sc0 + sO[gg][le] * sc1;
      Mt = Mn;
    }
    out[(size_t)b * EE + e] = Ot / St;  // St > 0: c=0 always valid (lengths >= 1)
  }
}

extern "C" void kernel_launch(void* const* d_in, const int* in_sizes, int n_in,
                              void* d_out, int out_size, void* d_ws, size_t ws_size,
                              hipStream_t stream) {
  const float* enc  = (const float*)d_in[0];
  const int*   lens = (const int*)d_in[1];
  const float* Wh   = (const float*)d_in[2];
  const float* bh   = (const float*)d_in[3];
  const float* Wc   = (const float*)d_in[4];
  float* out = (float*)d_out;

  const size_t wbytes = (size_t)512 * 512 * sizeof(unsigned short);
  int C = 64;  // Lc=32 -> one 32-row pass per item
  while (C > 8 && ws_size < (size_t)3 * BB * C * EE * sizeof(float) + 2 * wbytes + 64)
    C >>= 1;
  const int Lc = LL / C;

  float* pm = (float*)d_ws;
  float* ps = pm + (size_t)BB * C * EE;
  float* po = ps + (size_t)BB * C * EE;
  unsigned short* WhT = (unsigned short*)(po + (size_t)BB * C * EE);
  unsigned short* WcT = WhT + (size_t)512 * 512;
  int* q = (int*)(WcT + (size_t)512 * 512);

  prep_w<<<dim3(64, 2), 256, 0, stream>>>(Wh, Wc, WhT, WcT, q);
  attn_main<<<dim3(512), 512, 0, stream>>>(enc, lens, WhT, bh, WcT, pm, ps, po, q, C, Lc);
  attn_combine<<<dim3(8, BB), 256, 0, stream>>>(pm, ps, po, lens, out, C, Lc);
}